// Round 10
// baseline (252.447 us; speedup 1.0000x reference)
//
#include <hip/hip_runtime.h>
#include <hip/hip_bf16.h>

#define SEQ    4096
#define DIM    512
#define DIM3   1536
#define NH     16
#define HD     32
#define CHUNK  64
#define NCHUNK (SEQ / CHUNK)

typedef __attribute__((ext_vector_type(8))) short short8;
typedef __attribute__((ext_vector_type(4))) float f32x4;
typedef __attribute__((ext_vector_type(4))) unsigned short u16x4;
typedef __attribute__((ext_vector_type(4))) unsigned int u32x4;

__device__ inline unsigned short f2bf(float f) {
  unsigned u = __builtin_bit_cast(unsigned, f);
  unsigned r = (u + 0x7fff + ((u >> 16) & 1)) >> 16;
  return (unsigned short)r;
}
__device__ inline float bf2f(unsigned short b) {
  unsigned u = ((unsigned)b) << 16;
  return __builtin_bit_cast(float, u);
}

// ---------------------------------------------------------------------------
// Kernel 0 (R6-verbatim + counter zeroing): blocks 0..2047: x->bf16 |
// 2048..2815: W_qkv -> Wt bf16 transposed | 2816..3839: gates (f32-exact)
// ---------------------------------------------------------------------------
__global__ __launch_bounds__(256) void gl_cvt_gate(
    const float* __restrict__ x, const float* __restrict__ W,
    const float* __restrict__ Wa, const float* __restrict__ ba,
    unsigned short* __restrict__ xb, unsigned short* __restrict__ Wt,
    float2* __restrict__ graw, unsigned* __restrict__ counters) {
  __shared__ union {
    float wtile[32][33];
    struct { float xs[4][DIM]; float red[4][8][32]; } g;
  } sm;
  int b = blockIdx.x;
  if (b == 0 && threadIdx.x < 32) counters[threadIdx.x] = 0;  // p1done/scanDone
  if (b < 2048) {
    int i = b * 256 + threadIdx.x;
    float4 v = ((const float4*)x)[i];
    u16x4 o = {f2bf(v.x), f2bf(v.y), f2bf(v.z), f2bf(v.w)};
    ((u16x4*)xb)[i] = o;
  } else if (b < 2816) {
    b -= 2048;
    int bx = b % 48, by = b / 48;
    int tx = threadIdx.x & 31, ty = threadIdx.x >> 5;
    for (int i = ty; i < 32; i += 8)
      sm.wtile[i][tx] = W[(size_t)(by * 32 + i) * DIM3 + bx * 32 + tx];
    __syncthreads();
    for (int i = ty; i < 32; i += 8)
      Wt[(size_t)(bx * 32 + i) * DIM + by * 32 + tx] = f2bf(sm.wtile[tx][i]);
  } else {
    const int n0 = (b - 2816) * 4;
    const int tid = threadIdx.x;
    const float4* xv = (const float4*)(x + (size_t)n0 * DIM);
    float4* xsv = (float4*)&sm.g.xs[0][0];
    for (int i = tid; i < 512; i += 256) xsv[i] = xv[i];
    __syncthreads();
    const int o = tid & 31, s = tid >> 5;
    float pr[4] = {0, 0, 0, 0};
    for (int k = s * 64; k < s * 64 + 64; ++k) {
      float w = Wa[k * 32 + o];
      #pragma unroll
      for (int r = 0; r < 4; ++r) pr[r] += sm.g.xs[r][k] * w;
    }
    #pragma unroll
    for (int r = 0; r < 4; ++r) sm.g.red[r][s][o] = pr[r];
    __syncthreads();
    if (tid < 128) {
      int r = tid >> 5, oo = tid & 31;
      float acc = ba[oo];
      #pragma unroll
      for (int ss = 0; ss < 8; ++ss) acc += sm.g.red[r][ss][oo];
      sm.g.red[r][0][oo] = acc;
    }
    __syncthreads();
    if (tid < 64) {
      int r = tid >> 4, hh = tid & 15;
      float re = sm.g.red[r][0][2 * hh], im = sm.g.red[r][0][2 * hh + 1];
      float mag = sqrtf(re * re + im * im);
      float lml = -log1pf(expf(-mag));
      float ph = atan2f(im, re);
      graw[(size_t)hh * SEQ + n0 + r] = make_float2(lml, ph);
    }
  }
}

// ---------------------------------------------------------------------------
// Kernel 1 (R6-verbatim): qkv(bf16) = x @ W_qkv, 128x128, BK=64, 2-phase
// dbuf, counted vmcnt(8), bijective XCD swizzle.
// ---------------------------------------------------------------------------
#define GBM 128
#define GBN 128
#define GBK 64
__global__ __launch_bounds__(256) void gl_gemm_mfma(
    const unsigned short* __restrict__ A, const unsigned short* __restrict__ Bt,
    unsigned short* __restrict__ C) {
  __shared__ unsigned short As[2][GBM * GBK];
  __shared__ unsigned short Bs[2][GBM * GBK];
  const int tid = threadIdx.x;
  const int id = blockIdx.x;
  const int tile = (id & 7) * 48 + (id >> 3);
  const int by = tile / 12, bx = tile % 12;
  const int row0 = by * GBM, col0 = bx * GBN;
  const int wid = tid >> 6, lane = tid & 63;
  const int wr = wid >> 1, wc = wid & 1;
  const int lr = lane & 15, lg = lane >> 4;

  auto stage = [&](int buf, int t) {
    const int k0 = t * GBK;
    #pragma unroll
    for (int i = 0; i < 4; ++i) {
      int byteoff = i * 4096 + tid * 16;
      int row = byteoff >> 7;
      int logslot = ((byteoff >> 4) & 7) ^ (row & 7);
      const unsigned short* gp = A + (size_t)(row0 + row) * DIM + k0 + logslot * 8;
      __builtin_amdgcn_global_load_lds(
          (const __attribute__((address_space(1))) void*)gp,
          (__attribute__((address_space(3))) void*)((char*)As[buf] + byteoff),
          16, 0, 0);
    }
    #pragma unroll
    for (int i = 0; i < 4; ++i) {
      int byteoff = i * 4096 + tid * 16;
      int row = byteoff >> 7;
      int logslot = ((byteoff >> 4) & 7) ^ (row & 7);
      const unsigned short* gp = Bt + (size_t)(col0 + row) * DIM + k0 + logslot * 8;
      __builtin_amdgcn_global_load_lds(
          (const __attribute__((address_space(1))) void*)gp,
          (__attribute__((address_space(3))) void*)((char*)Bs[buf] + byteoff),
          16, 0, 0);
    }
  };

  f32x4 acc[4][4] = {};
  stage(0, 0);

  #pragma unroll
  for (int t = 0; t < 8; ++t) {
    const int p = t & 1;
    if (t < 7) {
      stage(p ^ 1, t + 1);
      asm volatile("s_waitcnt vmcnt(8)" ::: "memory");
    } else {
      asm volatile("s_waitcnt vmcnt(0)" ::: "memory");
    }
    __syncthreads();
    const char* AsB = (const char*)As[p];
    const char* BsB = (const char*)Bs[p];
    #pragma unroll
    for (int ks = 0; ks < 2; ++ks) {
      short8 af[4], bfr[4];
      #pragma unroll
      for (int m = 0; m < 4; ++m) {
        int row = wr * 64 + m * 16 + lr;
        int ps = (ks * 4 + lg) ^ (row & 7);
        af[m] = *(const short8*)(AsB + row * 128 + ps * 16);
      }
      #pragma unroll
      for (int n = 0; n < 4; ++n) {
        int col = wc * 64 + n * 16 + lr;
        int ps = (ks * 4 + lg) ^ (col & 7);
        bfr[n] = *(const short8*)(BsB + col * 128 + ps * 16);
      }
      #pragma unroll
      for (int m = 0; m < 4; ++m)
        #pragma unroll
        for (int n = 0; n < 4; ++n)
          acc[m][n] = __builtin_amdgcn_mfma_f32_16x16x32_bf16(
              af[m], bfr[n], acc[m][n], 0, 0, 0);
    }
    __syncthreads();
  }

  #pragma unroll
  for (int m = 0; m < 4; ++m)
    #pragma unroll
    for (int n = 0; n < 4; ++n) {
      int grow0 = row0 + wr * 64 + m * 16 + lg * 4;
      int gcol = col0 + wc * 64 + n * 16 + lr;
      #pragma unroll
      for (int j = 0; j < 4; ++j)
        C[(size_t)(grow0 + j) * DIM3 + gcol] = f2bf(acc[m][n][j]);
    }
}

// ---------------------------------------------------------------------------
// Kernel 2 (FUSED, counter-ordered, deadlock-free by ID monotonicity):
//   blocks 0..1023   : pass1 (R6 body)  -> p1done[h]++
//   blocks 1024..1151: scan  (R6 body), waits p1done[h]==64 -> scanDone[h]++
//   blocks 1152..2175: pass2 (R6 body), P^T BEFORE waiting scanDone[h]==8
// All 2176 blocks co-resident (9.2 KB LDS, 2 waves) -> pure dataflow.
// ---------------------------------------------------------------------------
__global__ __launch_bounds__(128) void gl_fused3(
    const unsigned short* __restrict__ qkv, const float2* __restrict__ graw,
    float2* __restrict__ LmPh, float* __restrict__ SLre,
    float* __restrict__ SLim, float2* __restrict__ Aprod,
    float2* __restrict__ Sin, float* __restrict__ out,
    unsigned* __restrict__ counters) {
  unsigned* p1done = counters;
  unsigned* scanDone = counters + 16;
  const int b = blockIdx.x;
  const int tid = threadIdx.x, w = tid >> 6, lane = tid & 63;
  const int lr = lane & 15, lg = lane >> 4;
  __shared__ float2 lmph[CHUNK];
  __shared__ unsigned Pp[32][68];

  if (b < 1024) {
    // ================= pass 1 =================
    const int c = b & (NCHUNK - 1), h = b >> 6;
    const int n0 = c * CHUNK;

    if (w == 0) {
      float2 g = graw[(size_t)h * SEQ + n0 + lane];
      float lm = g.x, ph = g.y;
      #pragma unroll
      for (int off = 1; off < 64; off <<= 1) {
        float a = __shfl_up(lm, off), p = __shfl_up(ph, off);
        if (lane >= off) { lm += a; ph += p; }
      }
      lmph[lane] = make_float2(lm, ph);
      LmPh[(size_t)h * SEQ + n0 + lane] = make_float2(lm, ph);
      if (lane == 63) {
        float e = __expf(lm);
        Aprod[h * NCHUNK + c] = make_float2(e * __cosf(ph), e * __sinf(ph));
      }
    }
    __syncthreads();
    const float2 end = lmph[63];

    const size_t rowb = (size_t)n0 * DIM3 + h * HD;
    f32x4 acc[2][2] = {};
    #pragma unroll
    for (int ks = 0; ks < 2; ++ks) {
      const int jb = ks * 32 + lg * 8;
      float wv[8];
      #pragma unroll
      for (int jj = 0; jj < 8; ++jj) {
        float2 lp = lmph[jb + jj];
        float e = __expf(end.x - lp.x);
        float an = end.y - lp.y;
        wv[jj] = e * (w == 0 ? __cosf(an) : __sinf(an));
      }
      short8 afr[2], bfr[2];
      #pragma unroll
      for (int mt = 0; mt < 2; ++mt) {
        int d = mt * 16 + lr;
        unsigned uu[4];
        #pragma unroll
        for (int q = 0; q < 4; ++q)
          uu[q] = (unsigned)f2bf(bf2f(qkv[rowb + (size_t)(jb + 2 * q) * DIM3 + DIM + d]) * wv[2 * q]) |
                  ((unsigned)f2bf(bf2f(qkv[rowb + (size_t)(jb + 2 * q + 1) * DIM3 + DIM + d]) * wv[2 * q + 1]) << 16);
        u32x4 t = {uu[0], uu[1], uu[2], uu[3]};
        afr[mt] = __builtin_bit_cast(short8, t);
      }
      #pragma unroll
      for (int nt = 0; nt < 2; ++nt) {
        int e_ = nt * 16 + lr;
        unsigned uu[4];
        #pragma unroll
        for (int q = 0; q < 4; ++q)
          uu[q] = (unsigned)qkv[rowb + (size_t)(jb + 2 * q) * DIM3 + 2 * DIM + e_] |
                  ((unsigned)qkv[rowb + (size_t)(jb + 2 * q + 1) * DIM3 + 2 * DIM + e_] << 16);
        u32x4 t = {uu[0], uu[1], uu[2], uu[3]};
        bfr[nt] = __builtin_bit_cast(short8, t);
      }
      #pragma unroll
      for (int mt = 0; mt < 2; ++mt)
        #pragma unroll
        for (int nt = 0; nt < 2; ++nt)
          acc[mt][nt] = __builtin_amdgcn_mfma_f32_16x16x32_bf16(
              afr[mt], bfr[nt], acc[mt][nt], 0, 0, 0);
    }
    float* dst = (w == 0) ? SLre : SLim;
    const size_t base = (size_t)(h * NCHUNK + c) * (HD * HD);
    #pragma unroll
    for (int mt = 0; mt < 2; ++mt)
      #pragma unroll
      for (int nt = 0; nt < 2; ++nt)
        #pragma unroll
        for (int r = 0; r < 4; ++r) {
          int d = mt * 16 + lg * 4 + r, e_ = nt * 16 + lr;
          dst[base + d * HD + e_] = acc[mt][nt][r];
        }
    __threadfence();
    if (tid == 0) atomicAdd(&p1done[h], 1u);

  } else if (b < 1152) {
    // ================= chunk-level scan =================
    const int idx = b - 1024;
    const int h = idx >> 3, oct = idx & 7;
    if (tid == 0) {
      while (__hip_atomic_load(&p1done[h], __ATOMIC_RELAXED,
                               __HIP_MEMORY_SCOPE_AGENT) < 64u)
        __builtin_amdgcn_s_sleep(8);
    }
    __syncthreads();
    __threadfence();

    const int elem = oct * 128 + tid;
    const size_t hb = (size_t)h * NCHUNK * (HD * HD) + elem;
    const float2* AP = Aprod + h * NCHUNK;
    float2 s = make_float2(0.f, 0.f);
    for (int cg = 0; cg < NCHUNK; cg += 8) {
      float lre[8], lim[8];
      float2 a[8];
      #pragma unroll
      for (int j = 0; j < 8; ++j) {
        size_t off = hb + (size_t)(cg + j) * (HD * HD);
        lre[j] = SLre[off];
        lim[j] = SLim[off];
        a[j] = AP[cg + j];
      }
      #pragma unroll
      for (int j = 0; j < 8; ++j) {
        Sin[hb + (size_t)(cg + j) * (HD * HD)] = s;
        float re = s.x, im = s.y;
        s.x = a[j].x * re - a[j].y * im + lre[j];
        s.y = a[j].x * im + a[j].y * re + lim[j];
      }
    }
    __threadfence();
    if (tid == 0) atomicAdd(&scanDone[h], 1u);

  } else {
    // ================= pass 2 =================
    const int idx = b - 1152;
    const int c = idx & (NCHUNK - 1), h = idx >> 6;
    const int n0 = c * CHUNK;
    const size_t rowb = (size_t)n0 * DIM3 + h * HD;

    // independent of scan: kf/qf loads + P^T (overlaps the wait)
    short8 kf[2], qf[4];
    #pragma unroll
    for (int mt = 0; mt < 2; ++mt) {
      int j = (2 * w + mt) * 16 + lr;
      kf[mt] = *(const short8*)(qkv + rowb + (size_t)j * DIM3 + DIM + lg * 8);
    }
    #pragma unroll
    for (int nt = 0; nt < 4; ++nt) {
      int n = nt * 16 + lr;
      qf[nt] = *(const short8*)(qkv + rowb + (size_t)n * DIM3 + lg * 8);
    }
    f32x4 pacc[2][4] = {};
    #pragma unroll
    for (int mt = 0; mt < 2; ++mt)
      #pragma unroll
      for (int nt = 0; nt < 4; ++nt)
        pacc[mt][nt] = __builtin_amdgcn_mfma_f32_16x16x32_bf16(
            kf[mt], qf[nt], pacc[mt][nt], 0, 0, 0);

    // wait for this head's Sin (and transitively its LmPh)
    if (tid == 0) {
      while (__hip_atomic_load(&scanDone[h], __ATOMIC_RELAXED,
                               __HIP_MEMORY_SCOPE_AGENT) < 8u)
        __builtin_amdgcn_s_sleep(8);
    }
    __syncthreads();
    __threadfence();
    if (tid < 64) lmph[tid] = LmPh[(size_t)h * SEQ + n0 + tid];
    __syncthreads();

    #pragma unroll
    for (int mt = 0; mt < 2; ++mt) {
      int jt = 2 * w + mt;
      #pragma unroll
      for (int r2 = 0; r2 < 2; ++r2) {
        int j0 = jt * 16 + lg * 4 + 2 * r2;
        float2 lj0 = lmph[j0], lj1 = lmph[j0 + 1];
        #pragma unroll
        for (int nt = 0; nt < 4; ++nt) {
          int n = nt * 16 + lr;
          float2 ln = lmph[n];
          float w0 = (j0 <= n) ? __expf(ln.x - lj0.x) * __cosf(ln.y - lj0.y) : 0.f;
          float w1 = (j0 + 1 <= n) ? __expf(ln.x - lj1.x) * __cosf(ln.y - lj1.y) : 0.f;
          Pp[jt * 8 + lg * 2 + r2][n] =
              (unsigned)f2bf(pacc[mt][nt][2 * r2] * w0) |
              ((unsigned)f2bf(pacc[mt][nt][2 * r2 + 1] * w1) << 16);
        }
      }
    }
    __syncthreads();

    const size_t soff = (size_t)(h * NCHUNK + c) * (HD * HD);
    short8 sre[2], sim[2];
    #pragma unroll
    for (int nt = 0; nt < 2; ++nt) {
      int e_ = nt * 16 + lr;
      unsigned ur[4], ui[4];
      #pragma unroll
      for (int q = 0; q < 4; ++q) {
        float2 s0 = Sin[soff + (size_t)(lg * 8 + 2 * q) * HD + e_];
        float2 s1 = Sin[soff + (size_t)(lg * 8 + 2 * q + 1) * HD + e_];
        ur[q] = (unsigned)f2bf(s0.x) | ((unsigned)f2bf(s1.x) << 16);
        ui[q] = (unsigned)f2bf(s0.y) | ((unsigned)f2bf(s1.y) << 16);
      }
      u32x4 tr = {ur[0], ur[1], ur[2], ur[3]};
      u32x4 ti = {ui[0], ui[1], ui[2], ui[3]};
      sre[nt] = __builtin_bit_cast(short8, tr);
      sim[nt] = __builtin_bit_cast(short8, ti);
    }
    f32x4 ore[2][2] = {}, oim[2][2] = {};
    #pragma unroll
    for (int mt = 0; mt < 2; ++mt)
      #pragma unroll
      for (int nt = 0; nt < 2; ++nt) {
        ore[mt][nt] = __builtin_amdgcn_mfma_f32_16x16x32_bf16(
            qf[2 * w + mt], sre[nt], ore[mt][nt], 0, 0, 0);
        oim[mt][nt] = __builtin_amdgcn_mfma_f32_16x16x32_bf16(
            qf[2 * w + mt], sim[nt], oim[mt][nt], 0, 0, 0);
      }
    f32x4 oacc[2][2];
    #pragma unroll
    for (int mt = 0; mt < 2; ++mt)
      #pragma unroll
      for (int r = 0; r < 4; ++r) {
        int n = (2 * w + mt) * 16 + lg * 4 + r;
        float2 ln = lmph[n];
        float eg = __expf(ln.x);
        float gr = eg * __cosf(ln.y), gi = eg * __sinf(ln.y);
        oacc[mt][0][r] = gr * ore[mt][0][r] - gi * oim[mt][0][r];
        oacc[mt][1][r] = gr * ore[mt][1][r] - gi * oim[mt][1][r];
      }
    #pragma unroll
    for (int ks = 0; ks < 2; ++ks) {
      short8 pa[2];
      #pragma unroll
      for (int mt = 0; mt < 2; ++mt) {
        int n_ = (2 * w + mt) * 16 + lr;
        unsigned u0 = Pp[ks * 16 + lg * 4 + 0][n_];
        unsigned u1 = Pp[ks * 16 + lg * 4 + 1][n_];
        unsigned u2 = Pp[ks * 16 + lg * 4 + 2][n_];
        unsigned u3 = Pp[ks * 16 + lg * 4 + 3][n_];
        u32x4 t = {u0, u1, u2, u3};
        pa[mt] = __builtin_bit_cast(short8, t);
      }
      const int jb = ks * 32 + lg * 8;
      short8 vf[2];
      #pragma unroll
      for (int nt = 0; nt < 2; ++nt) {
        int e_ = nt * 16 + lr;
        unsigned uu[4];
        #pragma unroll
        for (int q = 0; q < 4; ++q)
          uu[q] = (unsigned)qkv[rowb + (size_t)(jb + 2 * q) * DIM3 + 2 * DIM + e_] |
                  ((unsigned)qkv[rowb + (size_t)(jb + 2 * q + 1) * DIM3 + 2 * DIM + e_] << 16);
        u32x4 t = {uu[0], uu[1], uu[2], uu[3]};
        vf[nt] = __builtin_bit_cast(short8, t);
      }
      #pragma unroll
      for (int mt = 0; mt < 2; ++mt)
        #pragma unroll
        for (int nt = 0; nt < 2; ++nt)
          oacc[mt][nt] = __builtin_amdgcn_mfma_f32_16x16x32_bf16(
              pa[mt], vf[nt], oacc[mt][nt], 0, 0, 0);
    }
    #pragma unroll
    for (int mt = 0; mt < 2; ++mt)
      #pragma unroll
      for (int nt = 0; nt < 2; ++nt)
        #pragma unroll
        for (int r = 0; r < 4; ++r) {
          int n = (2 * w + mt) * 16 + lg * 4 + r;
          int e_ = nt * 16 + lr;
          out[(size_t)(n0 + n) * DIM + h * HD + e_] = oacc[mt][nt][r];
        }
  }
}

// ---------------------------------------------------------------------------
extern "C" void kernel_launch(void* const* d_in, const int* in_sizes, int n_in,
                              void* d_out, int out_size, void* d_ws,
                              size_t ws_size, hipStream_t stream) {
  const float* x     = (const float*)d_in[0];
  const float* W_qkv = (const float*)d_in[1];
  const float* W_a   = (const float*)d_in[2];
  const float* b_a   = (const float*)d_in[3];
  float* out = (float*)d_out;

  char* ws = (char*)d_ws;
  unsigned short* qkv  = (unsigned short*)ws;               // 12,582,912 B
  float2* graw  = (float2*)(ws + 12582912);                 //    524,288 B
  float2* LmPh  = (float2*)(ws + 13107200);                 //    524,288 B
  float*  SLre  = (float*)(ws + 13631488);                  //  4,194,304 B
  float*  SLim  = (float*)(ws + 17825792);                  //  4,194,304 B
  float2* Aprod = (float2*)(ws + 22020096);                 //      8,192 B
  float2* Sin   = (float2*)(ws + 22028288);                 //  8,388,608 B
  unsigned short* xb = (unsigned short*)(ws + 30416896);    //  4,194,304 B
  unsigned short* Wt = (unsigned short*)(ws + 34611200);    //  1,572,864 B
  unsigned* counters = (unsigned*)(ws + 36184064);          //        128 B

  // 0. conversions + gates; block 0 zeroes the dataflow counters
  gl_cvt_gate<<<3840, 256, 0, stream>>>(x, W_qkv, W_a, b_a, xb, Wt, graw,
                                        counters);
  // 1. qkv GEMM (MFMA bf16)
  gl_gemm_mfma<<<384, 256, 0, stream>>>(xb, Wt, qkv);
  // 2. fused pass1 -> scan -> pass2 (counter-ordered single launch)
  gl_fused3<<<2176, 128, 0, stream>>>(qkv, graw, LmPh, SLre, SLim, Aprod, Sin,
                                      out, counters);
}

// Round 11
// 53.387 us; speedup vs baseline: 4.7286x; 4.7286x over previous
//
#include <hip/hip_runtime.h>
#include <hip/hip_bf16.h>

#define SEQ    4096
#define DIM    512
#define DIM3   1536
#define NH     16
#define HD     32
#define CHUNK  64
#define NCHUNK (SEQ / CHUNK)

typedef __attribute__((ext_vector_type(8))) short short8;
typedef __attribute__((ext_vector_type(4))) float f32x4;
typedef __attribute__((ext_vector_type(4))) unsigned short u16x4;
typedef __attribute__((ext_vector_type(4))) unsigned int u32x4;

__device__ inline unsigned short f2bf(float f) {
  unsigned u = __builtin_bit_cast(unsigned, f);
  unsigned r = (u + 0x7fff + ((u >> 16) & 1)) >> 16;
  return (unsigned short)r;
}
__device__ inline float bf2f(unsigned short b) {
  unsigned u = ((unsigned)b) << 16;
  return __builtin_bit_cast(float, u);
}

// ---------------------------------------------------------------------------
// Kernel 0: blocks 0..1023 : gates for 4 rows each + x->bf16 for those rows
//           blocks 1024..1791: W_qkv -> Wt bf16 transposed
// ---------------------------------------------------------------------------
__global__ __launch_bounds__(256) void gl_cvt_gate(
    const float* __restrict__ x, const float* __restrict__ W,
    const float* __restrict__ Wa, const float* __restrict__ ba,
    unsigned short* __restrict__ xb, unsigned short* __restrict__ Wt,
    float2* __restrict__ graw) {
  __shared__ union {
    float wtile[32][33];
    struct { float xs[4][DIM]; float red[4][8][32]; } g;
  } sm;
  int b = blockIdx.x;
  if (b < 1024) {
    const int n0 = b * 4;
    const int tid = threadIdx.x;
    const float4* xv = (const float4*)(x + (size_t)n0 * DIM);
    u16x4* xbo = (u16x4*)(xb + (size_t)n0 * DIM);
    float4* xsv = (float4*)&sm.g.xs[0][0];
    for (int i = tid; i < 512; i += 256) {
      float4 v = xv[i];
      xsv[i] = v;
      u16x4 o = {f2bf(v.x), f2bf(v.y), f2bf(v.z), f2bf(v.w)};
      xbo[i] = o;
    }
    __syncthreads();
    const int o = tid & 31, s = tid >> 5;
    float pr[4] = {0, 0, 0, 0};
    for (int k = s * 64; k < s * 64 + 64; ++k) {
      float w = Wa[k * 32 + o];
      #pragma unroll
      for (int r = 0; r < 4; ++r) pr[r] += sm.g.xs[r][k] * w;
    }
    #pragma unroll
    for (int r = 0; r < 4; ++r) sm.g.red[r][s][o] = pr[r];
    __syncthreads();
    if (tid < 128) {
      int r = tid >> 5, oo = tid & 31;
      float acc = ba[oo];
      #pragma unroll
      for (int ss = 0; ss < 8; ++ss) acc += sm.g.red[r][ss][oo];
      sm.g.red[r][0][oo] = acc;
    }
    __syncthreads();
    if (tid < 64) {
      int r = tid >> 4, hh = tid & 15;
      float re = sm.g.red[r][0][2 * hh], im = sm.g.red[r][0][2 * hh + 1];
      float mag = sqrtf(re * re + im * im);
      float lml = -log1pf(expf(-mag));      // ln sigmoid(mag)
      float ph = atan2f(im, re);            // angle
      graw[(size_t)hh * SEQ + n0 + r] = make_float2(lml, ph);
    }
  } else {
    b -= 1024;
    int bx = b % 48, by = b / 48;
    int tx = threadIdx.x & 31, ty = threadIdx.x >> 5;
    for (int i = ty; i < 32; i += 8)
      sm.wtile[i][tx] = W[(size_t)(by * 32 + i) * DIM3 + bx * 32 + tx];
    __syncthreads();
    for (int i = ty; i < 32; i += 8)
      Wt[(size_t)(bx * 32 + i) * DIM + by * 32 + tx] = f2bf(sm.wtile[tx][i]);
  }
}

// ---------------------------------------------------------------------------
// Kernel 1 (R6-verbatim): qkv(bf16) = x @ W_qkv, 128x128, BK=64, 2-phase
// dbuf, counted vmcnt(8), bijective XCD swizzle (384 = 8 x 48).
// ---------------------------------------------------------------------------
#define GBM 128
#define GBN 128
#define GBK 64
__global__ __launch_bounds__(256) void gl_gemm_mfma(
    const unsigned short* __restrict__ A, const unsigned short* __restrict__ Bt,
    unsigned short* __restrict__ C) {
  __shared__ unsigned short As[2][GBM * GBK];
  __shared__ unsigned short Bs[2][GBM * GBK];
  const int tid = threadIdx.x;
  const int id = blockIdx.x;
  const int tile = (id & 7) * 48 + (id >> 3);
  const int by = tile / 12, bx = tile % 12;
  const int row0 = by * GBM, col0 = bx * GBN;
  const int wid = tid >> 6, lane = tid & 63;
  const int wr = wid >> 1, wc = wid & 1;
  const int lr = lane & 15, lg = lane >> 4;

  auto stage = [&](int buf, int t) {
    const int k0 = t * GBK;
    #pragma unroll
    for (int i = 0; i < 4; ++i) {
      int byteoff = i * 4096 + tid * 16;
      int row = byteoff >> 7;
      int logslot = ((byteoff >> 4) & 7) ^ (row & 7);
      const unsigned short* gp = A + (size_t)(row0 + row) * DIM + k0 + logslot * 8;
      __builtin_amdgcn_global_load_lds(
          (const __attribute__((address_space(1))) void*)gp,
          (__attribute__((address_space(3))) void*)((char*)As[buf] + byteoff),
          16, 0, 0);
    }
    #pragma unroll
    for (int i = 0; i < 4; ++i) {
      int byteoff = i * 4096 + tid * 16;
      int row = byteoff >> 7;
      int logslot = ((byteoff >> 4) & 7) ^ (row & 7);
      const unsigned short* gp = Bt + (size_t)(col0 + row) * DIM + k0 + logslot * 8;
      __builtin_amdgcn_global_load_lds(
          (const __attribute__((address_space(1))) void*)gp,
          (__attribute__((address_space(3))) void*)((char*)Bs[buf] + byteoff),
          16, 0, 0);
    }
  };

  f32x4 acc[4][4] = {};
  stage(0, 0);

  #pragma unroll
  for (int t = 0; t < 8; ++t) {
    const int p = t & 1;
    if (t < 7) {
      stage(p ^ 1, t + 1);
      asm volatile("s_waitcnt vmcnt(8)" ::: "memory");
    } else {
      asm volatile("s_waitcnt vmcnt(0)" ::: "memory");
    }
    __syncthreads();
    const char* AsB = (const char*)As[p];
    const char* BsB = (const char*)Bs[p];
    #pragma unroll
    for (int ks = 0; ks < 2; ++ks) {
      short8 af[4], bfr[4];
      #pragma unroll
      for (int m = 0; m < 4; ++m) {
        int row = wr * 64 + m * 16 + lr;
        int ps = (ks * 4 + lg) ^ (row & 7);
        af[m] = *(const short8*)(AsB + row * 128 + ps * 16);
      }
      #pragma unroll
      for (int n = 0; n < 4; ++n) {
        int col = wc * 64 + n * 16 + lr;
        int ps = (ks * 4 + lg) ^ (col & 7);
        bfr[n] = *(const short8*)(BsB + col * 128 + ps * 16);
      }
      #pragma unroll
      for (int m = 0; m < 4; ++m)
        #pragma unroll
        for (int n = 0; n < 4; ++n)
          acc[m][n] = __builtin_amdgcn_mfma_f32_16x16x32_bf16(
              af[m], bfr[n], acc[m][n], 0, 0, 0);
    }
    __syncthreads();
  }

  #pragma unroll
  for (int m = 0; m < 4; ++m)
    #pragma unroll
    for (int n = 0; n < 4; ++n) {
      int grow0 = row0 + wr * 64 + m * 16 + lg * 4;
      int gcol = col0 + wc * 64 + n * 16 + lr;
      #pragma unroll
      for (int j = 0; j < 4; ++j)
        C[(size_t)(grow0 + j) * DIM3 + gcol] = f2bf(acc[m][n][j]);
    }
}

// ---------------------------------------------------------------------------
// Kernel 2 (pass1, R6-verbatim): chunk-local prefix (Lm,Ph) via shfl scan;
// S_loc = (w∘K)^T V via 16x16x32 MFMA. wave0 re, wave1 im.
// ---------------------------------------------------------------------------
__global__ __launch_bounds__(128) void gl_pass1(
    const unsigned short* __restrict__ qkv, const float2* __restrict__ graw,
    float2* __restrict__ LmPh, float* __restrict__ SLre,
    float* __restrict__ SLim, float2* __restrict__ Aprod) {
  const int b = blockIdx.x;
  const int c = b & (NCHUNK - 1), h = b >> 6;
  const int tid = threadIdx.x, w = tid >> 6, lane = tid & 63;
  const int lr = lane & 15, lg = lane >> 4;
  const int n0 = c * CHUNK;
  __shared__ float2 lmph[CHUNK];

  float2 g = graw[(size_t)h * SEQ + n0 + lane];
  float lm = g.x, ph = g.y;
  #pragma unroll
  for (int off = 1; off < 64; off <<= 1) {
    float a = __shfl_up(lm, off), p = __shfl_up(ph, off);
    if (lane >= off) { lm += a; ph += p; }
  }
  if (w == 0) {
    LmPh[(size_t)h * SEQ + n0 + lane] = make_float2(lm, ph);
    lmph[lane] = make_float2(lm, ph);
    if (lane == 63) {
      float e = __expf(lm);
      Aprod[h * NCHUNK + c] = make_float2(e * __cosf(ph), e * __sinf(ph));
    }
  }
  __syncthreads();
  const float2 end = lmph[63];

  const size_t rowb = (size_t)n0 * DIM3 + h * HD;
  f32x4 acc[2][2] = {};
  #pragma unroll
  for (int ks = 0; ks < 2; ++ks) {
    const int jb = ks * 32 + lg * 8;
    float wv[8];
    #pragma unroll
    for (int jj = 0; jj < 8; ++jj) {
      float2 lp = lmph[jb + jj];
      float e = __expf(end.x - lp.x);
      float an = end.y - lp.y;
      wv[jj] = e * (w == 0 ? __cosf(an) : __sinf(an));
    }
    short8 afr[2], bfr[2];
    #pragma unroll
    for (int mt = 0; mt < 2; ++mt) {
      int d = mt * 16 + lr;
      unsigned u0, u1, u2, u3;
      #define LD_KW(q) ((unsigned)f2bf(bf2f(qkv[rowb + (size_t)(jb + 2*(q)) * DIM3 + DIM + d]) * wv[2*(q)]) | \
                        ((unsigned)f2bf(bf2f(qkv[rowb + (size_t)(jb + 2*(q)+1) * DIM3 + DIM + d]) * wv[2*(q)+1]) << 16))
      u0 = LD_KW(0); u1 = LD_KW(1); u2 = LD_KW(2); u3 = LD_KW(3);
      #undef LD_KW
      u32x4 t = {u0, u1, u2, u3};
      afr[mt] = __builtin_bit_cast(short8, t);
    }
    #pragma unroll
    for (int nt = 0; nt < 2; ++nt) {
      int e_ = nt * 16 + lr;
      unsigned u0, u1, u2, u3;
      #define LD_V(q) ((unsigned)qkv[rowb + (size_t)(jb + 2*(q)) * DIM3 + 2*DIM + e_] | \
                       ((unsigned)qkv[rowb + (size_t)(jb + 2*(q)+1) * DIM3 + 2*DIM + e_] << 16))
      u0 = LD_V(0); u1 = LD_V(1); u2 = LD_V(2); u3 = LD_V(3);
      #undef LD_V
      u32x4 t = {u0, u1, u2, u3};
      bfr[nt] = __builtin_bit_cast(short8, t);
    }
    #pragma unroll
    for (int mt = 0; mt < 2; ++mt)
      #pragma unroll
      for (int nt = 0; nt < 2; ++nt)
        acc[mt][nt] = __builtin_amdgcn_mfma_f32_16x16x32_bf16(
            afr[mt], bfr[nt], acc[mt][nt], 0, 0, 0);
  }
  float* dst = (w == 0) ? SLre : SLim;
  const size_t base = (size_t)(h * NCHUNK + c) * (HD * HD);
  #pragma unroll
  for (int mt = 0; mt < 2; ++mt)
    #pragma unroll
    for (int nt = 0; nt < 2; ++nt)
      #pragma unroll
      for (int r = 0; r < 4; ++r) {
        int d = mt * 16 + lg * 4 + r, e_ = nt * 16 + lr;
        dst[base + d * HD + e_] = acc[mt][nt][r];
      }
}

// ---------------------------------------------------------------------------
// Kernel 3: chunk-level scan; emits Sin as PACKED bf16 d-pairs (re/im).
// Rounding identical to what pass2 previously applied -> zero accuracy delta.
// ---------------------------------------------------------------------------
__global__ __launch_bounds__(128) void gl_scan_chunks(
    const float* __restrict__ SLre, const float* __restrict__ SLim,
    const float2* __restrict__ Aprod, unsigned* __restrict__ SinPre,
    unsigned* __restrict__ SinPim) {
  const int h = blockIdx.x >> 3;
  const int oct = blockIdx.x & 7;
  const int tid = threadIdx.x;
  const int elem = oct * 128 + tid;
  const int e = elem & 31;
  const int qp = elem >> 6;                 // (d>>1) for the even-d lane
  const bool lo = !(tid & 32);              // lane owns even d; partner +32
  const size_t hb = (size_t)h * NCHUNK * (HD * HD) + elem;
  const float2* AP = Aprod + h * NCHUNK;
  float2 s = make_float2(0.f, 0.f);
  for (int cg = 0; cg < NCHUNK; cg += 8) {
    float lre[8], lim[8];
    float2 a[8];
    #pragma unroll
    for (int j = 0; j < 8; ++j) {
      size_t off = hb + (size_t)(cg + j) * (HD * HD);
      lre[j] = SLre[off];
      lim[j] = SLim[off];
      a[j] = AP[cg + j];
    }
    #pragma unroll
    for (int j = 0; j < 8; ++j) {
      float px = __shfl_xor(s.x, 32);
      float py = __shfl_xor(s.y, 32);
      if (lo) {
        size_t wo = (size_t)(h * NCHUNK + cg + j) * 512 + qp * 32 + e;
        SinPre[wo] = (unsigned)f2bf(s.x) | ((unsigned)f2bf(px) << 16);
        SinPim[wo] = (unsigned)f2bf(s.y) | ((unsigned)f2bf(py) << 16);
      }
      float re = s.x, im = s.y;
      s.x = a[j].x * re - a[j].y * im + lre[j];
      s.y = a[j].x * im + a[j].y * re + lim[j];
    }
  }
}

// ---------------------------------------------------------------------------
// Kernel 4 (pass2, R7-verbatim): P^T = K Q^T -> weight W(n,j) -> pack bf16 ->
// LDS; O = Re(G_n (Q S_in)) + (P∘W) V (all MFMA). Sin read pre-packed bf16.
// ---------------------------------------------------------------------------
__global__ __launch_bounds__(128) void gl_pass2(
    const unsigned short* __restrict__ qkv, const float2* __restrict__ LmPh,
    const unsigned* __restrict__ SinPre, const unsigned* __restrict__ SinPim,
    float* __restrict__ out) {
  const int b = blockIdx.x;
  const int c = b & (NCHUNK - 1), h = b >> 6;
  const int tid = threadIdx.x, w = tid >> 6, lane = tid & 63;
  const int lr = lane & 15, lg = lane >> 4;
  const int n0 = c * CHUNK;
  __shared__ float2 lmph[CHUNK];
  __shared__ unsigned Pp[32][68];
  if (tid < 64) lmph[tid] = LmPh[(size_t)h * SEQ + n0 + tid];
  __syncthreads();

  const size_t rowb = (size_t)n0 * DIM3 + h * HD;
  short8 kf[2], qf[4];
  #pragma unroll
  for (int mt = 0; mt < 2; ++mt) {
    int j = (2 * w + mt) * 16 + lr;
    kf[mt] = *(const short8*)(qkv + rowb + (size_t)j * DIM3 + DIM + lg * 8);
  }
  #pragma unroll
  for (int nt = 0; nt < 4; ++nt) {
    int n = nt * 16 + lr;
    qf[nt] = *(const short8*)(qkv + rowb + (size_t)n * DIM3 + lg * 8);
  }
  f32x4 pacc[2][4] = {};
  #pragma unroll
  for (int mt = 0; mt < 2; ++mt)
    #pragma unroll
    for (int nt = 0; nt < 4; ++nt)
      pacc[mt][nt] = __builtin_amdgcn_mfma_f32_16x16x32_bf16(
          kf[mt], qf[nt], pacc[mt][nt], 0, 0, 0);

  #pragma unroll
  for (int mt = 0; mt < 2; ++mt) {
    int jt = 2 * w + mt;
    #pragma unroll
    for (int r2 = 0; r2 < 2; ++r2) {
      int j0 = jt * 16 + lg * 4 + 2 * r2;
      float2 lj0 = lmph[j0], lj1 = lmph[j0 + 1];
      #pragma unroll
      for (int nt = 0; nt < 4; ++nt) {
        int n = nt * 16 + lr;
        float2 ln = lmph[n];
        float w0 = (j0 <= n) ? __expf(ln.x - lj0.x) * __cosf(ln.y - lj0.y) : 0.f;
        float w1 = (j0 + 1 <= n) ? __expf(ln.x - lj1.x) * __cosf(ln.y - lj1.y) : 0.f;
        Pp[jt * 8 + lg * 2 + r2][n] =
            (unsigned)f2bf(pacc[mt][nt][2 * r2] * w0) |
            ((unsigned)f2bf(pacc[mt][nt][2 * r2 + 1] * w1) << 16);
      }
    }
  }
  __syncthreads();

  const size_t s512 = (size_t)(h * NCHUNK + c) * 512;
  short8 sre[2], sim[2];
  #pragma unroll
  for (int nt = 0; nt < 2; ++nt) {
    int e_ = nt * 16 + lr;
    unsigned ur[4], ui[4];
    #pragma unroll
    for (int q = 0; q < 4; ++q) {
      ur[q] = SinPre[s512 + (size_t)(lg * 4 + q) * 32 + e_];
      ui[q] = SinPim[s512 + (size_t)(lg * 4 + q) * 32 + e_];
    }
    u32x4 tr = {ur[0], ur[1], ur[2], ur[3]};
    u32x4 ti = {ui[0], ui[1], ui[2], ui[3]};
    sre[nt] = __builtin_bit_cast(short8, tr);
    sim[nt] = __builtin_bit_cast(short8, ti);
  }
  f32x4 ore[2][2] = {}, oim[2][2] = {};
  #pragma unroll
  for (int mt = 0; mt < 2; ++mt)
    #pragma unroll
    for (int nt = 0; nt < 2; ++nt) {
      ore[mt][nt] = __builtin_amdgcn_mfma_f32_16x16x32_bf16(
          qf[2 * w + mt], sre[nt], ore[mt][nt], 0, 0, 0);
      oim[mt][nt] = __builtin_amdgcn_mfma_f32_16x16x32_bf16(
          qf[2 * w + mt], sim[nt], oim[mt][nt], 0, 0, 0);
    }
  f32x4 oacc[2][2];
  #pragma unroll
  for (int mt = 0; mt < 2; ++mt)
    #pragma unroll
    for (int r = 0; r < 4; ++r) {
      int n = (2 * w + mt) * 16 + lg * 4 + r;
      float2 ln = lmph[n];
      float eg = __expf(ln.x);
      float gr = eg * __cosf(ln.y), gi = eg * __sinf(ln.y);
      oacc[mt][0][r] = gr * ore[mt][0][r] - gi * oim[mt][0][r];
      oacc[mt][1][r] = gr * ore[mt][1][r] - gi * oim[mt][1][r];
    }
  #pragma unroll
  for (int ks = 0; ks < 2; ++ks) {
    short8 pa[2];
    #pragma unroll
    for (int mt = 0; mt < 2; ++mt) {
      int n_ = (2 * w + mt) * 16 + lr;
      unsigned u0 = Pp[ks * 16 + lg * 4 + 0][n_];
      unsigned u1 = Pp[ks * 16 + lg * 4 + 1][n_];
      unsigned u2 = Pp[ks * 16 + lg * 4 + 2][n_];
      unsigned u3 = Pp[ks * 16 + lg * 4 + 3][n_];
      u32x4 t = {u0, u1, u2, u3};
      pa[mt] = __builtin_bit_cast(short8, t);
    }
    const int jb = ks * 32 + lg * 8;
    short8 vf[2];
    #pragma unroll
    for (int nt = 0; nt < 2; ++nt) {
      int e_ = nt * 16 + lr;
      unsigned u0, u1, u2, u3;
      #define LD_V(q) ((unsigned)qkv[rowb + (size_t)(jb + 2*(q)) * DIM3 + 2*DIM + e_] | \
                       ((unsigned)qkv[rowb + (size_t)(jb + 2*(q)+1) * DIM3 + 2*DIM + e_] << 16))
      u0 = LD_V(0); u1 = LD_V(1); u2 = LD_V(2); u3 = LD_V(3);
      #undef LD_V
      u32x4 t = {u0, u1, u2, u3};
      vf[nt] = __builtin_bit_cast(short8, t);
    }
    #pragma unroll
    for (int mt = 0; mt < 2; ++mt)
      #pragma unroll
      for (int nt = 0; nt < 2; ++nt)
        oacc[mt][nt] = __builtin_amdgcn_mfma_f32_16x16x32_bf16(
            pa[mt], vf[nt], oacc[mt][nt], 0, 0, 0);
  }
  #pragma unroll
  for (int mt = 0; mt < 2; ++mt)
    #pragma unroll
    for (int nt = 0; nt < 2; ++nt)
      #pragma unroll
      for (int r = 0; r < 4; ++r) {
        int n = (2 * w + mt) * 16 + lg * 4 + r;
        int e_ = nt * 16 + lr;
        out[(size_t)(n0 + n) * DIM + h * HD + e_] = oacc[mt][nt][r];
      }
}

// ---------------------------------------------------------------------------
extern "C" void kernel_launch(void* const* d_in, const int* in_sizes, int n_in,
                              void* d_out, int out_size, void* d_ws,
                              size_t ws_size, hipStream_t stream) {
  const float* x     = (const float*)d_in[0];
  const float* W_qkv = (const float*)d_in[1];
  const float* W_a   = (const float*)d_in[2];
  const float* b_a   = (const float*)d_in[3];
  float* out = (float*)d_out;

  char* ws = (char*)d_ws;
  unsigned short* qkv  = (unsigned short*)ws;               // 12,582,912 B
  float2* graw  = (float2*)(ws + 12582912);                 //    524,288 B
  float2* LmPh  = (float2*)(ws + 13107200);                 //    524,288 B
  float*  SLre  = (float*)(ws + 13631488);                  //  4,194,304 B
  float*  SLim  = (float*)(ws + 17825792);                  //  4,194,304 B
  float2* Aprod = (float2*)(ws + 22020096);                 //      8,192 B
  unsigned* SinPre = (unsigned*)(ws + 22028288);            //  2,097,152 B
  unsigned* SinPim = (unsigned*)(ws + 24125440);            //  2,097,152 B
  unsigned short* xb = (unsigned short*)(ws + 26222592);    //  4,194,304 B
  unsigned short* Wt = (unsigned short*)(ws + 30416896);    //  1,572,864 B

  // 0. gates + x->bf16 (x read once) ; W transpose
  gl_cvt_gate<<<1792, 256, 0, stream>>>(x, W_qkv, W_a, b_a, xb, Wt, graw);
  // 1. qkv GEMM (R6-exact 128x128, counted vmcnt(8))
  gl_gemm_mfma<<<384, 256, 0, stream>>>(xb, Wt, qkv);
  // 2. per-chunk local state (MFMA)
  gl_pass1<<<NCHUNK * NH, 128, 0, stream>>>(qkv, graw, LmPh, SLre, SLim, Aprod);
  // 3. chunk-level scan (packed bf16 Sin)
  gl_scan_chunks<<<128, 128, 0, stream>>>(SLre, SLim, Aprod, SinPre, SinPim);
  // 4. replay + output (MFMA)
  gl_pass2<<<NCHUNK * NH, 128, 0, stream>>>(qkv, LmPh, SinPre, SinPim, out);
}

// Round 12
// 51.650 us; speedup vs baseline: 4.8877x; 1.0336x over previous
//
#include <hip/hip_runtime.h>
#include <hip/hip_bf16.h>

#define SEQ    4096
#define DIM    512
#define DIM3   1536
#define NH     16
#define HD     32
#define CHUNK  64
#define NCHUNK (SEQ / CHUNK)

typedef __attribute__((ext_vector_type(8))) short short8;
typedef __attribute__((ext_vector_type(4))) float f32x4;
typedef __attribute__((ext_vector_type(4))) unsigned short u16x4;
typedef __attribute__((ext_vector_type(4))) unsigned int u32x4;

__device__ inline unsigned short f2bf(float f) {
  unsigned u = __builtin_bit_cast(unsigned, f);
  unsigned r = (u + 0x7fff + ((u >> 16) & 1)) >> 16;
  return (unsigned short)r;
}
__device__ inline float bf2f(unsigned short b) {
  unsigned u = ((unsigned)b) << 16;
  return __builtin_bit_cast(float, u);
}

// ---------------------------------------------------------------------------
// Kernel 0: blocks 0..2047: x->bf16 | 2048..2815: W_qkv -> Wt bf16 transposed
//           | 2816..3839: gates as (ln sigmoid(|a|), angle(a))  [f32-exact]
// ---------------------------------------------------------------------------
__global__ __launch_bounds__(256) void gl_cvt_gate(
    const float* __restrict__ x, const float* __restrict__ W,
    const float* __restrict__ Wa, const float* __restrict__ ba,
    unsigned short* __restrict__ xb, unsigned short* __restrict__ Wt,
    float2* __restrict__ graw) {
  __shared__ union {
    float wtile[32][33];
    struct { float xs[4][DIM]; float red[4][8][32]; } g;
  } sm;
  int b = blockIdx.x;
  if (b < 2048) {
    int i = b * 256 + threadIdx.x;
    float4 v = ((const float4*)x)[i];
    u16x4 o = {f2bf(v.x), f2bf(v.y), f2bf(v.z), f2bf(v.w)};
    ((u16x4*)xb)[i] = o;
  } else if (b < 2816) {
    b -= 2048;
    int bx = b % 48, by = b / 48;
    int tx = threadIdx.x & 31, ty = threadIdx.x >> 5;
    for (int i = ty; i < 32; i += 8)
      sm.wtile[i][tx] = W[(size_t)(by * 32 + i) * DIM3 + bx * 32 + tx];
    __syncthreads();
    for (int i = ty; i < 32; i += 8)
      Wt[(size_t)(bx * 32 + i) * DIM + by * 32 + tx] = f2bf(sm.wtile[tx][i]);
  } else {
    const int n0 = (b - 2816) * 4;
    const int tid = threadIdx.x;
    const float4* xv = (const float4*)(x + (size_t)n0 * DIM);
    float4* xsv = (float4*)&sm.g.xs[0][0];
    for (int i = tid; i < 512; i += 256) xsv[i] = xv[i];
    __syncthreads();
    const int o = tid & 31, s = tid >> 5;
    float pr[4] = {0, 0, 0, 0};
    for (int k = s * 64; k < s * 64 + 64; ++k) {
      float w = Wa[k * 32 + o];
      #pragma unroll
      for (int r = 0; r < 4; ++r) pr[r] += sm.g.xs[r][k] * w;
    }
    #pragma unroll
    for (int r = 0; r < 4; ++r) sm.g.red[r][s][o] = pr[r];
    __syncthreads();
    if (tid < 128) {
      int r = tid >> 5, oo = tid & 31;
      float acc = ba[oo];
      #pragma unroll
      for (int ss = 0; ss < 8; ++ss) acc += sm.g.red[r][ss][oo];
      sm.g.red[r][0][oo] = acc;
    }
    __syncthreads();
    if (tid < 64) {
      int r = tid >> 4, hh = tid & 15;
      float re = sm.g.red[r][0][2 * hh], im = sm.g.red[r][0][2 * hh + 1];
      float mag = sqrtf(re * re + im * im);
      float lml = -log1pf(expf(-mag));      // ln sigmoid(mag)
      float ph = atan2f(im, re);            // angle
      graw[(size_t)hh * SEQ + n0 + r] = make_float2(lml, ph);
    }
  }
}

// ---------------------------------------------------------------------------
// Kernel 1: qkv(bf16) = x @ W_qkv, bf16 MFMA, 128x128, BK=64, 2-phase dbuf
// with counted vmcnt(8); bijective XCD swizzle.
// ---------------------------------------------------------------------------
#define GBM 128
#define GBN 128
#define GBK 64
__global__ __launch_bounds__(256) void gl_gemm_mfma(
    const unsigned short* __restrict__ A, const unsigned short* __restrict__ Bt,
    unsigned short* __restrict__ C) {
  __shared__ unsigned short As[2][GBM * GBK];
  __shared__ unsigned short Bs[2][GBM * GBK];
  const int tid = threadIdx.x;
  const int id = blockIdx.x;
  const int tile = (id & 7) * 48 + (id >> 3);
  const int by = tile / 12, bx = tile % 12;
  const int row0 = by * GBM, col0 = bx * GBN;
  const int wid = tid >> 6, lane = tid & 63;
  const int wr = wid >> 1, wc = wid & 1;
  const int lr = lane & 15, lg = lane >> 4;

  auto stage = [&](int buf, int t) {
    const int k0 = t * GBK;
    #pragma unroll
    for (int i = 0; i < 4; ++i) {
      int byteoff = i * 4096 + tid * 16;
      int row = byteoff >> 7;
      int logslot = ((byteoff >> 4) & 7) ^ (row & 7);
      const unsigned short* gp = A + (size_t)(row0 + row) * DIM + k0 + logslot * 8;
      __builtin_amdgcn_global_load_lds(
          (const __attribute__((address_space(1))) void*)gp,
          (__attribute__((address_space(3))) void*)((char*)As[buf] + byteoff),
          16, 0, 0);
    }
    #pragma unroll
    for (int i = 0; i < 4; ++i) {
      int byteoff = i * 4096 + tid * 16;
      int row = byteoff >> 7;
      int logslot = ((byteoff >> 4) & 7) ^ (row & 7);
      const unsigned short* gp = Bt + (size_t)(col0 + row) * DIM + k0 + logslot * 8;
      __builtin_amdgcn_global_load_lds(
          (const __attribute__((address_space(1))) void*)gp,
          (__attribute__((address_space(3))) void*)((char*)Bs[buf] + byteoff),
          16, 0, 0);
    }
  };

  f32x4 acc[4][4] = {};
  stage(0, 0);

  #pragma unroll
  for (int t = 0; t < 8; ++t) {
    const int p = t & 1;
    if (t < 7) {
      stage(p ^ 1, t + 1);
      asm volatile("s_waitcnt vmcnt(8)" ::: "memory");
    } else {
      asm volatile("s_waitcnt vmcnt(0)" ::: "memory");
    }
    __syncthreads();
    const char* AsB = (const char*)As[p];
    const char* BsB = (const char*)Bs[p];
    #pragma unroll
    for (int ks = 0; ks < 2; ++ks) {
      short8 af[4], bfr[4];
      #pragma unroll
      for (int m = 0; m < 4; ++m) {
        int row = wr * 64 + m * 16 + lr;
        int ps = (ks * 4 + lg) ^ (row & 7);
        af[m] = *(const short8*)(AsB + row * 128 + ps * 16);
      }
      #pragma unroll
      for (int n = 0; n < 4; ++n) {
        int col = wc * 64 + n * 16 + lr;
        int ps = (ks * 4 + lg) ^ (col & 7);
        bfr[n] = *(const short8*)(BsB + col * 128 + ps * 16);
      }
      #pragma unroll
      for (int m = 0; m < 4; ++m)
        #pragma unroll
        for (int n = 0; n < 4; ++n)
          acc[m][n] = __builtin_amdgcn_mfma_f32_16x16x32_bf16(
              af[m], bfr[n], acc[m][n], 0, 0, 0);
    }
    __syncthreads();
  }

  #pragma unroll
  for (int m = 0; m < 4; ++m)
    #pragma unroll
    for (int n = 0; n < 4; ++n) {
      int grow0 = row0 + wr * 64 + m * 16 + lg * 4;
      int gcol = col0 + wc * 64 + n * 16 + lr;
      #pragma unroll
      for (int j = 0; j < 4; ++j)
        C[(size_t)(grow0 + j) * DIM3 + gcol] = f2bf(acc[m][n][j]);
    }
}

// ---------------------------------------------------------------------------
// Kernel 2 (pass1, MFMA): per (h,c): chunk-local prefix (Lm,Ph) via shfl scan;
// S_loc = (w∘K)^T V with w_j = suffix gate product, via 16x16x32 MFMA.
// wave0 -> real part, wave1 -> imag part. Also emits Aprod and LmPh.
// ---------------------------------------------------------------------------
__global__ __launch_bounds__(128) void gl_pass1(
    const unsigned short* __restrict__ qkv, const float2* __restrict__ graw,
    float2* __restrict__ LmPh, float* __restrict__ SLre,
    float* __restrict__ SLim, float2* __restrict__ Aprod) {
  const int b = blockIdx.x;
  const int c = b & (NCHUNK - 1), h = b >> 6;
  const int tid = threadIdx.x, w = tid >> 6, lane = tid & 63;
  const int lr = lane & 15, lg = lane >> 4;
  const int n0 = c * CHUNK;
  __shared__ float2 lmph[CHUNK];

  float2 g = graw[(size_t)h * SEQ + n0 + lane];
  float lm = g.x, ph = g.y;
  #pragma unroll
  for (int off = 1; off < 64; off <<= 1) {
    float a = __shfl_up(lm, off), p = __shfl_up(ph, off);
    if (lane >= off) { lm += a; ph += p; }
  }
  if (w == 0) {
    LmPh[(size_t)h * SEQ + n0 + lane] = make_float2(lm, ph);
    lmph[lane] = make_float2(lm, ph);
    if (lane == 63) {
      float e = __expf(lm);
      Aprod[h * NCHUNK + c] = make_float2(e * __cosf(ph), e * __sinf(ph));
    }
  }
  __syncthreads();
  const float2 end = lmph[63];

  const size_t rowb = (size_t)n0 * DIM3 + h * HD;
  f32x4 acc[2][2] = {};
  #pragma unroll
  for (int ks = 0; ks < 2; ++ks) {
    const int jb = ks * 32 + lg * 8;
    float wv[8];
    #pragma unroll
    for (int jj = 0; jj < 8; ++jj) {
      float2 lp = lmph[jb + jj];
      float e = __expf(end.x - lp.x);
      float an = end.y - lp.y;
      wv[jj] = e * (w == 0 ? __cosf(an) : __sinf(an));
    }
    short8 afr[2], bfr[2];
    #pragma unroll
    for (int mt = 0; mt < 2; ++mt) {
      int d = mt * 16 + lr;
      unsigned u0, u1, u2, u3;
      #define LD_KW(q) ((unsigned)f2bf(bf2f(qkv[rowb + (size_t)(jb + 2*(q)) * DIM3 + DIM + d]) * wv[2*(q)]) | \
                        ((unsigned)f2bf(bf2f(qkv[rowb + (size_t)(jb + 2*(q)+1) * DIM3 + DIM + d]) * wv[2*(q)+1]) << 16))
      u0 = LD_KW(0); u1 = LD_KW(1); u2 = LD_KW(2); u3 = LD_KW(3);
      #undef LD_KW
      u32x4 t = {u0, u1, u2, u3};
      afr[mt] = __builtin_bit_cast(short8, t);
    }
    #pragma unroll
    for (int nt = 0; nt < 2; ++nt) {
      int e_ = nt * 16 + lr;
      unsigned u0, u1, u2, u3;
      #define LD_V(q) ((unsigned)qkv[rowb + (size_t)(jb + 2*(q)) * DIM3 + 2*DIM + e_] | \
                       ((unsigned)qkv[rowb + (size_t)(jb + 2*(q)+1) * DIM3 + 2*DIM + e_] << 16))
      u0 = LD_V(0); u1 = LD_V(1); u2 = LD_V(2); u3 = LD_V(3);
      #undef LD_V
      u32x4 t = {u0, u1, u2, u3};
      bfr[nt] = __builtin_bit_cast(short8, t);
    }
    #pragma unroll
    for (int mt = 0; mt < 2; ++mt)
      #pragma unroll
      for (int nt = 0; nt < 2; ++nt)
        acc[mt][nt] = __builtin_amdgcn_mfma_f32_16x16x32_bf16(
            afr[mt], bfr[nt], acc[mt][nt], 0, 0, 0);
  }
  float* dst = (w == 0) ? SLre : SLim;
  const size_t base = (size_t)(h * NCHUNK + c) * (HD * HD);
  #pragma unroll
  for (int mt = 0; mt < 2; ++mt)
    #pragma unroll
    for (int nt = 0; nt < 2; ++nt)
      #pragma unroll
      for (int r = 0; r < 4; ++r) {
        int d = mt * 16 + lg * 4 + r, e_ = nt * 16 + lr;
        dst[base + d * HD + e_] = acc[mt][nt][r];
      }
}

// ---------------------------------------------------------------------------
// Kernel 3: chunk-level scan (split re/im Sloc inputs, f32 Sin)
// ---------------------------------------------------------------------------
__global__ __launch_bounds__(128) void gl_scan_chunks(
    const float* __restrict__ SLre, const float* __restrict__ SLim,
    const float2* __restrict__ Aprod, float2* __restrict__ Sin) {
  const int h = blockIdx.x >> 3;
  const int oct = blockIdx.x & 7;
  const size_t hb = (size_t)h * NCHUNK * (HD * HD) + oct * 128 + threadIdx.x;
  const float2* AP = Aprod + h * NCHUNK;
  float2 s = make_float2(0.f, 0.f);
  for (int cg = 0; cg < NCHUNK; cg += 8) {
    float lre[8], lim[8];
    float2 a[8];
    #pragma unroll
    for (int j = 0; j < 8; ++j) {
      size_t off = hb + (size_t)(cg + j) * (HD * HD);
      lre[j] = SLre[off];
      lim[j] = SLim[off];
      a[j] = AP[cg + j];
    }
    #pragma unroll
    for (int j = 0; j < 8; ++j) {
      Sin[hb + (size_t)(cg + j) * (HD * HD)] = s;
      float re = s.x, im = s.y;
      s.x = a[j].x * re - a[j].y * im + lre[j];
      s.y = a[j].x * im + a[j].y * re + lim[j];
    }
  }
}

// ---------------------------------------------------------------------------
// Kernel 4 (pass2, MFMA): per (h,c):
//   P^T = K Q^T (MFMA) -> weight W(n,j)=1[j<=n]exp(Lm_n-Lm_j)cos(Ph_n-Ph_j),
//   pack bf16 j-pairs -> LDS Pp; O = Re(G_n (Q S_in)) + (P∘W) V  (all MFMA).
// ---------------------------------------------------------------------------
__global__ __launch_bounds__(128) void gl_pass2(
    const unsigned short* __restrict__ qkv, const float2* __restrict__ LmPh,
    const float2* __restrict__ Sin, float* __restrict__ out) {
  const int b = blockIdx.x;
  const int c = b & (NCHUNK - 1), h = b >> 6;
  const int tid = threadIdx.x, w = tid >> 6, lane = tid & 63;
  const int lr = lane & 15, lg = lane >> 4;
  const int n0 = c * CHUNK;
  __shared__ float2 lmph[CHUNK];
  __shared__ unsigned Pp[32][68];   // packed bf16 j-pairs, padded (bank-clean)
  if (tid < 64) lmph[tid] = LmPh[(size_t)h * SEQ + n0 + tid];
  __syncthreads();

  const size_t rowb = (size_t)n0 * DIM3 + h * HD;
  short8 kf[2], qf[4];
  #pragma unroll
  for (int mt = 0; mt < 2; ++mt) {
    int j = (2 * w + mt) * 16 + lr;
    kf[mt] = *(const short8*)(qkv + rowb + (size_t)j * DIM3 + DIM + lg * 8);
  }
  #pragma unroll
  for (int nt = 0; nt < 4; ++nt) {
    int n = nt * 16 + lr;
    qf[nt] = *(const short8*)(qkv + rowb + (size_t)n * DIM3 + lg * 8);
  }
  f32x4 pacc[2][4] = {};
  #pragma unroll
  for (int mt = 0; mt < 2; ++mt)
    #pragma unroll
    for (int nt = 0; nt < 4; ++nt)
      pacc[mt][nt] = __builtin_amdgcn_mfma_f32_16x16x32_bf16(
          kf[mt], qf[nt], pacc[mt][nt], 0, 0, 0);

  #pragma unroll
  for (int mt = 0; mt < 2; ++mt) {
    int jt = 2 * w + mt;
    #pragma unroll
    for (int r2 = 0; r2 < 2; ++r2) {
      int j0 = jt * 16 + lg * 4 + 2 * r2;
      float2 lj0 = lmph[j0], lj1 = lmph[j0 + 1];
      #pragma unroll
      for (int nt = 0; nt < 4; ++nt) {
        int n = nt * 16 + lr;
        float2 ln = lmph[n];
        float w0 = (j0 <= n) ? __expf(ln.x - lj0.x) * __cosf(ln.y - lj0.y) : 0.f;
        float w1 = (j0 + 1 <= n) ? __expf(ln.x - lj1.x) * __cosf(ln.y - lj1.y) : 0.f;
        Pp[jt * 8 + lg * 2 + r2][n] =
            (unsigned)f2bf(pacc[mt][nt][2 * r2] * w0) |
            ((unsigned)f2bf(pacc[mt][nt][2 * r2 + 1] * w1) << 16);
      }
    }
  }
  __syncthreads();

  // inter: QS = Q @ S_in (re & im)
  const size_t soff = (size_t)(h * NCHUNK + c) * (HD * HD);
  short8 sre[2], sim[2];
  #pragma unroll
  for (int nt = 0; nt < 2; ++nt) {
    int e_ = nt * 16 + lr;
    unsigned ur[4], ui[4];
    #pragma unroll
    for (int q = 0; q < 4; ++q) {
      float2 s0 = Sin[soff + (size_t)(lg * 8 + 2 * q) * HD + e_];
      float2 s1 = Sin[soff + (size_t)(lg * 8 + 2 * q + 1) * HD + e_];
      ur[q] = (unsigned)f2bf(s0.x) | ((unsigned)f2bf(s1.x) << 16);
      ui[q] = (unsigned)f2bf(s0.y) | ((unsigned)f2bf(s1.y) << 16);
    }
    u32x4 tr = {ur[0], ur[1], ur[2], ur[3]};
    u32x4 ti = {ui[0], ui[1], ui[2], ui[3]};
    sre[nt] = __builtin_bit_cast(short8, tr);
    sim[nt] = __builtin_bit_cast(short8, ti);
  }
  f32x4 ore[2][2] = {}, oim[2][2] = {};
  #pragma unroll
  for (int mt = 0; mt < 2; ++mt)
    #pragma unroll
    for (int nt = 0; nt < 2; ++nt) {
      ore[mt][nt] = __builtin_amdgcn_mfma_f32_16x16x32_bf16(
          qf[2 * w + mt], sre[nt], ore[mt][nt], 0, 0, 0);
      oim[mt][nt] = __builtin_amdgcn_mfma_f32_16x16x32_bf16(
          qf[2 * w + mt], sim[nt], oim[mt][nt], 0, 0, 0);
    }
  f32x4 oacc[2][2];
  #pragma unroll
  for (int mt = 0; mt < 2; ++mt)
    #pragma unroll
    for (int r = 0; r < 4; ++r) {
      int n = (2 * w + mt) * 16 + lg * 4 + r;
      float2 ln = lmph[n];
      float eg = __expf(ln.x);
      float gr = eg * __cosf(ln.y), gi = eg * __sinf(ln.y);
      oacc[mt][0][r] = gr * ore[mt][0][r] - gi * oim[mt][0][r];
      oacc[mt][1][r] = gr * ore[mt][1][r] - gi * oim[mt][1][r];
    }
  #pragma unroll
  for (int ks = 0; ks < 2; ++ks) {
    short8 pa[2];
    #pragma unroll
    for (int mt = 0; mt < 2; ++mt) {
      int n_ = (2 * w + mt) * 16 + lr;
      unsigned u0 = Pp[ks * 16 + lg * 4 + 0][n_];
      unsigned u1 = Pp[ks * 16 + lg * 4 + 1][n_];
      unsigned u2 = Pp[ks * 16 + lg * 4 + 2][n_];
      unsigned u3 = Pp[ks * 16 + lg * 4 + 3][n_];
      u32x4 t = {u0, u1, u2, u3};
      pa[mt] = __builtin_bit_cast(short8, t);
    }
    const int jb = ks * 32 + lg * 8;
    short8 vf[2];
    #pragma unroll
    for (int nt = 0; nt < 2; ++nt) {
      int e_ = nt * 16 + lr;
      unsigned u0, u1, u2, u3;
      #define LD_V(q) ((unsigned)qkv[rowb + (size_t)(jb + 2*(q)) * DIM3 + 2*DIM + e_] | \
                       ((unsigned)qkv[rowb + (size_t)(jb + 2*(q)+1) * DIM3 + 2*DIM + e_] << 16))
      u0 = LD_V(0); u1 = LD_V(1); u2 = LD_V(2); u3 = LD_V(3);
      #undef LD_V
      u32x4 t = {u0, u1, u2, u3};
      vf[nt] = __builtin_bit_cast(short8, t);
    }
    #pragma unroll
    for (int mt = 0; mt < 2; ++mt)
      #pragma unroll
      for (int nt = 0; nt < 2; ++nt)
        oacc[mt][nt] = __builtin_amdgcn_mfma_f32_16x16x32_bf16(
            pa[mt], vf[nt], oacc[mt][nt], 0, 0, 0);
  }
  #pragma unroll
  for (int mt = 0; mt < 2; ++mt)
    #pragma unroll
    for (int nt = 0; nt < 2; ++nt)
      #pragma unroll
      for (int r = 0; r < 4; ++r) {
        int n = (2 * w + mt) * 16 + lg * 4 + r;
        int e_ = nt * 16 + lr;
        out[(size_t)(n0 + n) * DIM + h * HD + e_] = oacc[mt][nt][r];
      }
}

// ---------------------------------------------------------------------------
extern "C" void kernel_launch(void* const* d_in, const int* in_sizes, int n_in,
                              void* d_out, int out_size, void* d_ws,
                              size_t ws_size, hipStream_t stream) {
  const float* x     = (const float*)d_in[0];
  const float* W_qkv = (const float*)d_in[1];
  const float* W_a   = (const float*)d_in[2];
  const float* b_a   = (const float*)d_in[3];
  float* out = (float*)d_out;

  char* ws = (char*)d_ws;
  unsigned short* qkv  = (unsigned short*)ws;               // 12,582,912 B
  float2* graw  = (float2*)(ws + 12582912);                 //    524,288 B
  float2* LmPh  = (float2*)(ws + 13107200);                 //    524,288 B
  float*  SLre  = (float*)(ws + 13631488);                  //  4,194,304 B
  float*  SLim  = (float*)(ws + 17825792);                  //  4,194,304 B
  float2* Aprod = (float2*)(ws + 22020096);                 //      8,192 B
  float2* Sin   = (float2*)(ws + 22028288);                 //  8,388,608 B
  unsigned short* xb = (unsigned short*)(ws + 30416896);    //  4,194,304 B
  unsigned short* Wt = (unsigned short*)(ws + 34611200);    //  1,572,864 B

  gl_cvt_gate<<<3840, 256, 0, stream>>>(x, W_qkv, W_a, b_a, xb, Wt, graw);
  gl_gemm_mfma<<<384, 256, 0, stream>>>(xb, Wt, qkv);
  gl_pass1<<<NCHUNK * NH, 128, 0, stream>>>(qkv, graw, LmPh, SLre, SLim, Aprod);
  gl_scan_chunks<<<128, 128, 0, stream>>>(SLre, SLim, Aprod, Sin);
  gl_pass2<<<NCHUNK * NH, 128, 0, stream>>>(qkv, LmPh, Sin, out);
}